// Round 5
// baseline (528.890 us; speedup 1.0000x reference)
//
#include <hip/hip_runtime.h>

#define D 128
#define HW 64      // histogram workgroups
#define HS 10016   // histogram stride (>= N, multiple of 32)
#define FW 128     // fill workgroups (dst-range owners)

// round-to-nearest-even fp32 -> bf16 bits
__device__ __forceinline__ unsigned short f2bf(float f) {
  unsigned int u = __float_as_uint(f);
  return (unsigned short)((u + 0x7FFFu + ((u >> 16) & 1u)) >> 16);
}

// ---------------- setup kernels (no global atomics anywhere) ----------------

// Per-wg LDS degree histogram + batch histogram + pack pk[i] = src | dst<<14.
// Requires N < 16384 (here N = 10000 < HS).
__global__ __launch_bounds__(256) void k_hist(const int* __restrict__ ei, int E, int N,
                                              const int* __restrict__ batch,
                                              int* __restrict__ pk,
                                              int* __restrict__ g_hist,
                                              int* __restrict__ g_bh) {
  __shared__ int h[HS];
  __shared__ int bh[64];
  for (int j = threadIdx.x; j < HS; j += 256) h[j] = 0;
  if (threadIdx.x < 64) bh[threadIdx.x] = 0;
  __syncthreads();
  int stride = HW * 256;
  int idx0 = blockIdx.x * 256 + threadIdx.x;
  for (int i = idx0; i < E; i += stride) {
    int s = ei[i], d = ei[E + i];
    pk[i] = s | (d << 14);
    atomicAdd(&h[d], 1);
  }
  for (int i = idx0; i < N; i += stride) {
    pk[E + i] = i | (i << 14);          // self-loop record
    atomicAdd(&bh[batch[i]], 1);
  }
  __syncthreads();
  for (int j = threadIdx.x; j < HS; j += 256) g_hist[blockIdx.x * HS + j] = h[j];
  if (threadIdx.x < 64) g_bh[blockIdx.x * 64 + threadIdx.x] = bh[threadIdx.x];
}

// Column-sum the per-wg histograms -> cnt (incl. self-loop), dinv, cntB, accB=0.
__global__ __launch_bounds__(256) void k_merge(const int* __restrict__ g_hist,
                                               const int* __restrict__ g_bh,
                                               int* cnt, float* dinv,
                                               int* cntB, float* accB, int N, int B) {
  int j = blockIdx.x * 256 + threadIdx.x;
  if (j < N) {
    int c = 1;                               // self-loop
    #pragma unroll 8
    for (int w = 0; w < HW; ++w) c += g_hist[w * HS + j];
    cnt[j] = c;
    dinv[j] = rsqrtf((float)c);
  }
  if (j < B) {
    int c = 0;
    for (int w = 0; w < HW; ++w) c += g_bh[w * 64 + j];
    cntB[j] = c;
    accB[j] = 0.f;
  }
}

// exclusive scan of cnt -> offs; offs[N]=total. Single block.
__global__ __launch_bounds__(1024) void k_scan(const int* __restrict__ cnt,
                                               int* offs, int N) {
  __shared__ int wsum[16];
  __shared__ int carry_s;
  int tid = threadIdx.x, wid = tid >> 6, lane = tid & 63;
  if (tid == 0) carry_s = 0;
  __syncthreads();
  for (int base = 0; base < N; base += 1024) {
    int i = base + tid;
    int v = (i < N) ? cnt[i] : 0;
    int x = v;
    #pragma unroll
    for (int s = 1; s < 64; s <<= 1) {
      int t = __shfl_up(x, s);
      if (lane >= s) x += t;
    }
    if (lane == 63) wsum[wid] = x;
    __syncthreads();
    int woff = 0;
    for (int w = 0; w < wid; ++w) woff += wsum[w];
    int carry = carry_s;
    if (i < N) offs[i] = carry + woff + x - v;
    __syncthreads();
    if (tid == 1023) carry_s = carry + woff + x;
  }
  __syncthreads();
  if (tid == 0) offs[N] = carry_s;
}

// CSR fill, dst-range ownership: wg owns dst in [lo,hi); cursors live in LDS
// (no global atomics). Each wg scans all of pk (L2-resident) and places only
// its own records; epair writes confined to the wg's private window.
__global__ __launch_bounds__(256) void k_fill(const int* __restrict__ pk, int M, int N,
                                              const float* __restrict__ dinv,
                                              const int* __restrict__ offs,
                                              float2* __restrict__ epair) {
  __shared__ int cur[128];
  int wg = blockIdx.x;
  int lo = (int)(((long long)wg * N) / FW);
  int hi = (int)(((long long)(wg + 1) * N) / FW);
  int rs = hi - lo;
  for (int j = threadIdx.x; j < rs; j += 256) cur[j] = offs[lo + j];
  __syncthreads();
  int M4 = M >> 2;
  for (int i = threadIdx.x; i < M4; i += 256) {
    int4 r4 = ((const int4*)pk)[i];
    #pragma unroll
    for (int u = 0; u < 4; ++u) {
      int rec = (u == 0) ? r4.x : (u == 1) ? r4.y : (u == 2) ? r4.z : r4.w;
      int d = rec >> 14;
      if (d >= lo && d < hi) {
        int s = rec & 0x3FFF;
        int q = atomicAdd(&cur[d - lo], 1);
        epair[q] = make_float2(__int_as_float(s), dinv[s] * dinv[d]);
      }
    }
  }
  for (int i = (M4 << 2) + threadIdx.x; i < M; i += 256) {
    int rec = pk[i];
    int d = rec >> 14;
    if (d >= lo && d < hi) {
      int s = rec & 0x3FFF;
      int q = atomicAdd(&cur[d - lo], 1);
      epair[q] = make_float2(__int_as_float(s), dinv[s] * dinv[d]);
    }
  }
}

// ---------------- GEMM: C[N x 128](bf16) = A[N x 128](f32) @ W[128 x 128](f32) ----------------
__global__ __launch_bounds__(256) void k_gemm(const float* __restrict__ A,
                                              const float* __restrict__ W,
                                              unsigned short* __restrict__ C, int N) {
  __shared__ float As[32][36];
  __shared__ float Ws[32][128];
  int tid = threadIdx.x;
  int tx = tid & 31;
  int ty = tid >> 5;
  int r0 = blockIdx.x * 32;
  float acc[4][4] = {};

  for (int k0 = 0; k0 < 128; k0 += 32) {
    for (int i = tid; i < 1024; i += 256) {
      int kk = i >> 5, j4 = i & 31;
      float4 w = *(const float4*)(W + (size_t)(k0 + kk) * 128 + j4 * 4);
      *(float4*)(&Ws[kk][j4 * 4]) = w;
    }
    {
      int r = tid >> 3, k4 = tid & 7;
      int row = r0 + r;
      float4 a = make_float4(0.f, 0.f, 0.f, 0.f);
      if (row < N) a = *(const float4*)(A + (size_t)row * 128 + k0 + k4 * 4);
      As[k4 * 4 + 0][r] = a.x;
      As[k4 * 4 + 1][r] = a.y;
      As[k4 * 4 + 2][r] = a.z;
      As[k4 * 4 + 3][r] = a.w;
    }
    __syncthreads();
    #pragma unroll
    for (int k = 0; k < 32; ++k) {
      float4 a = *(const float4*)(&As[k][ty * 4]);
      float4 b = *(const float4*)(&Ws[k][tx * 4]);
      float av[4] = {a.x, a.y, a.z, a.w};
      float bv[4] = {b.x, b.y, b.z, b.w};
      #pragma unroll
      for (int i = 0; i < 4; ++i)
        #pragma unroll
        for (int j = 0; j < 4; ++j)
          acc[i][j] = fmaf(av[i], bv[j], acc[i][j]);
    }
    __syncthreads();
  }
  #pragma unroll
  for (int i = 0; i < 4; ++i) {
    int row = r0 + ty * 4 + i;
    if (row < N) {
      ushort4 o;
      o.x = f2bf(acc[i][0]); o.y = f2bf(acc[i][1]);
      o.z = f2bf(acc[i][2]); o.w = f2bf(acc[i][3]);
      *(ushort4*)(C + (size_t)row * 128 + tx * 4) = o;
    }
  }
}

// ---------------- aggregation ----------------
// One wave per node; edge metadata at wave-uniform addresses (node in SGPR via
// readfirstlane); 16-deep two-phase unroll for gather MLP.
__device__ __forceinline__ void agg_core(const unsigned short* __restrict__ t,
                                         const float2* __restrict__ epair,
                                         int beg, int end, int lane,
                                         float& ax, float& ay) {
  int e = beg;
  for (; e + 16 <= end; e += 16) {
    float2 ep[16];
    #pragma unroll
    for (int u = 0; u < 16; ++u) ep[u] = epair[e + u];
    #pragma unroll
    for (int u = 0; u < 16; ++u) {
      int   s = __float_as_int(ep[u].x);
      float w = ep[u].y;
      unsigned int v = *(const unsigned int*)(t + ((size_t)s << 7) + (lane << 1));
      ax = fmaf(w, __uint_as_float(v << 16), ax);
      ay = fmaf(w, __uint_as_float(v & 0xFFFF0000u), ay);
    }
  }
  for (; e < end; ++e) {
    float2 ep = epair[e];
    int   s = __float_as_int(ep.x);
    float w = ep.y;
    unsigned int v = *(const unsigned int*)(t + ((size_t)s << 7) + (lane << 1));
    ax = fmaf(w, __uint_as_float(v << 16), ax);
    ay = fmaf(w, __uint_as_float(v & 0xFFFF0000u), ay);
  }
}

__global__ __launch_bounds__(256) void k_agg(const unsigned short* __restrict__ t,
                                             const float2* __restrict__ epair,
                                             const int* __restrict__ offs,
                                             const float* __restrict__ bias,
                                             float* __restrict__ hout, int N, int relu) {
  int node = __builtin_amdgcn_readfirstlane(blockIdx.x * 4 + (threadIdx.x >> 6));
  int lane = threadIdx.x & 63;
  if (node >= N) return;
  int beg = offs[node], end = offs[node + 1];
  float ax = 0.f, ay = 0.f;
  agg_core(t, epair, beg, end, lane, ax, ay);
  float2 b = *(const float2*)(bias + lane * 2);
  ax += b.x; ay += b.y;
  if (relu) { ax = fmaxf(ax, 0.f); ay = fmaxf(ay, 0.f); }
  *(float2*)(hout + (size_t)node * 128 + lane * 2) = make_float2(ax, ay);
}

__global__ __launch_bounds__(256) void k_agg_pool(const unsigned short* __restrict__ t,
                                                  const float2* __restrict__ epair,
                                                  const int* __restrict__ offs,
                                                  const float* __restrict__ bias,
                                                  const float* __restrict__ Wp,
                                                  const int* __restrict__ batch,
                                                  float* accB, int N) {
  int node = __builtin_amdgcn_readfirstlane(blockIdx.x * 4 + (threadIdx.x >> 6));
  int lane = threadIdx.x & 63;
  if (node >= N) return;
  int beg = offs[node], end = offs[node + 1];
  float ax = 0.f, ay = 0.f;
  agg_core(t, epair, beg, end, lane, ax, ay);
  float2 b = *(const float2*)(bias + lane * 2);
  float2 wp = *(const float2*)(Wp + lane * 2);
  float p = (ax + b.x) * wp.x + (ay + b.y) * wp.y;
  #pragma unroll
  for (int s = 32; s; s >>= 1) p += __shfl_xor(p, s);
  if (lane == 0) atomicAdd(&accB[batch[node]], p);
}

__global__ __launch_bounds__(64) void k_final(const float* __restrict__ accB,
                                              const int* __restrict__ cntB,
                                              const float* __restrict__ bp,
                                              float* out, int B) {
  int b = blockIdx.x * 64 + threadIdx.x;
  if (b < B) {
    float c = (float)(cntB[b] > 1 ? cntB[b] : 1);
    out[b] = accB[b] / c + bp[0];
  }
}

// ---------------- launch ----------------

extern "C" void kernel_launch(void* const* d_in, const int* in_sizes, int n_in,
                              void* d_out, int out_size, void* d_ws, size_t ws_size,
                              hipStream_t stream) {
  const float* x    = (const float*)d_in[0];
  const int*   ei   = (const int*)d_in[1];
  const int*   batch= (const int*)d_in[2];
  const float* W1   = (const float*)d_in[3];
  const float* b1   = (const float*)d_in[4];
  const float* W2   = (const float*)d_in[5];
  const float* b2   = (const float*)d_in[6];
  const float* W3   = (const float*)d_in[7];
  const float* b3   = (const float*)d_in[8];
  const float* Wp   = (const float*)d_in[9];
  const float* bp   = (const float*)d_in[10];
  float* out = (float*)d_out;

  int N = in_sizes[0] / D;
  int E = in_sizes[1] / 2;
  int B = out_size;
  int M = E + N;

  char* p = (char*)d_ws;
  float2* epair  = (float2*)p;          p += (size_t)M * 8;
  float* hbuf    = (float*)p;           p += (size_t)N * D * 4;
  unsigned short* tbuf = (unsigned short*)p; p += (size_t)N * D * 2;
  int*   pk      = (int*)p;             p += (size_t)M * 4;
  int*   g_hist  = (int*)p;             p += (size_t)HW * HS * 4;
  int*   g_bh    = (int*)p;             p += (size_t)HW * 64 * 4;
  int*   cnt     = (int*)p;             p += (size_t)N * 4;
  int*   offs    = (int*)p;             p += (size_t)(N + 1) * 4;
  float* dinv    = (float*)p;           p += (size_t)N * 4;
  float* accB    = (float*)p;           p += (size_t)B * 4;
  int*   cntB    = (int*)p;             p += (size_t)B * 4;

  int gG  = (N + 31) / 32;
  int gA  = (N + 3) / 4;
  int gMg = (N + 255) / 256;   // k_merge covers j < N (B << N)

  k_hist <<<HW, 256, 0, stream>>>(ei, E, N, batch, pk, g_hist, g_bh);
  k_merge<<<gMg, 256, 0, stream>>>(g_hist, g_bh, cnt, dinv, cntB, accB, N, B);
  k_scan <<<1, 1024, 0, stream>>>(cnt, offs, N);
  k_fill <<<FW, 256, 0, stream>>>(pk, M, N, dinv, offs, epair);

  k_gemm<<<gG, 256, 0, stream>>>(x, W1, tbuf, N);
  k_agg <<<gA, 256, 0, stream>>>(tbuf, epair, offs, b1, hbuf, N, 1);
  k_gemm<<<gG, 256, 0, stream>>>(hbuf, W2, tbuf, N);
  k_agg <<<gA, 256, 0, stream>>>(tbuf, epair, offs, b2, hbuf, N, 1);
  k_gemm<<<gG, 256, 0, stream>>>(hbuf, W3, tbuf, N);
  k_agg_pool<<<gA, 256, 0, stream>>>(tbuf, epair, offs, b3, Wp, batch, accB, N);
  k_final<<<(B + 63) / 64, 64, 0, stream>>>(accB, cntB, bp, out, B);
}

// Round 7
// 281.843 us; speedup vs baseline: 1.8765x; 1.8765x over previous
//
#include <hip/hip_runtime.h>

#define D 128
#define HS 10016          // histogram stride (>= N)
#define CSHIFT 13         // 8192-record contiguous chunks
#define CSZ (1 << CSHIFT)

// round-to-nearest-even fp32 -> bf16 bits
__device__ __forceinline__ unsigned short f2bf(float f) {
  unsigned int u = __float_as_uint(f);
  return (unsigned short)((u + 0x7FFFu + ((u >> 16) & 1u)) >> 16);
}

// ---------------- setup: counting-sort CSR build, zero global atomics ----------------

// Per-chunk LDS histogram over dst + batch histogram + pack pk + per-record rank
// within its (chunk, dst) cell. Chunk w = records [w*8192, (w+1)*8192).
// Records 0..E-1 are edges; E..M-1 are self-loops (src=dst=i-E). N < 16384.
__global__ __launch_bounds__(256) void k_hist(const int* __restrict__ ei, int E, int M,
                                              const int* __restrict__ batch,
                                              int* __restrict__ pk,
                                              unsigned short* __restrict__ rank16,
                                              int* __restrict__ g_hist,
                                              int* __restrict__ g_bh) {
  __shared__ int h[HS];
  __shared__ int bh[64];
  for (int j = threadIdx.x; j < HS; j += 256) h[j] = 0;
  if (threadIdx.x < 64) bh[threadIdx.x] = 0;
  __syncthreads();
  int w = blockIdx.x;
  int i0 = w << CSHIFT;
  int i1 = i0 + CSZ; if (i1 > M) i1 = M;
  for (int i = i0 + threadIdx.x; i < i1; i += 256) {
    int s, d;
    if (i < E) { s = ei[i]; d = ei[E + i]; }
    else { s = i - E; d = s; atomicAdd(&bh[batch[s]], 1); }
    pk[i] = s | (d << 14);
    int r = atomicAdd(&h[d], 1);       // rank within (chunk, dst); <= 8192
    rank16[i] = (unsigned short)r;
  }
  __syncthreads();
  for (int j = threadIdx.x; j < HS; j += 256) g_hist[w * HS + j] = h[j];
  if (threadIdx.x < 64) g_bh[blockIdx.x * 64 + threadIdx.x] = bh[threadIdx.x];
}

// Per-dst: sequential scan over chunks turns g_hist into colprefix (in place),
// total -> cnt/dinv. Also merges batch hists, zeroes accB.
__global__ __launch_bounds__(256) void k_merge(int* __restrict__ g_hist,
                                               const int* __restrict__ g_bh,
                                               int* cnt, float* dinv,
                                               int* cntB, float* accB,
                                               int N, int B, int HW) {
  int j = blockIdx.x * 256 + threadIdx.x;
  if (j < N) {
    int run = 0;
    for (int w = 0; w < HW; ++w) {
      int idx = w * HS + j;
      int t = g_hist[idx];
      g_hist[idx] = run;               // exclusive prefix over chunks
      run += t;
    }
    cnt[j] = run;                      // includes self-loop -> >= 1
    dinv[j] = rsqrtf((float)run);
  }
  if (j < B) {
    int c = 0;
    for (int w = 0; w < HW; ++w) c += g_bh[w * 64 + j];
    cntB[j] = c;
    accB[j] = 0.f;
  }
}

// exclusive scan of cnt -> offs; offs[N]=total. Single block.
__global__ __launch_bounds__(1024) void k_scan(const int* __restrict__ cnt,
                                               int* offs, int N) {
  __shared__ int wsum[16];
  __shared__ int carry_s;
  int tid = threadIdx.x, wid = tid >> 6, lane = tid & 63;
  if (tid == 0) carry_s = 0;
  __syncthreads();
  for (int base = 0; base < N; base += 1024) {
    int i = base + tid;
    int v = (i < N) ? cnt[i] : 0;
    int x = v;
    #pragma unroll
    for (int s = 1; s < 64; s <<= 1) {
      int t = __shfl_up(x, s);
      if (lane >= s) x += t;
    }
    if (lane == 63) wsum[wid] = x;
    __syncthreads();
    int woff = 0;
    for (int w = 0; w < wid; ++w) woff += wsum[w];
    int carry = carry_s;
    if (i < N) offs[i] = carry + woff + x - v;
    __syncthreads();
    if (tid == 1023) carry_s = carry + woff + x;
  }
  __syncthreads();
  if (tid == 0) offs[N] = carry_s;
}

// CSR fill: fully parallel, ZERO atomics. pos = offs[d] + colpre[chunk][d] + rank.
// blockIdx&7 partitions dst ranges so each epair line has a single-XCD writer
// (keeps R4's write-locality win); pk re-read 8x from L2 (2.6 MB, resident).
__global__ __launch_bounds__(256) void k_fill(const int* __restrict__ pk,
                                              const unsigned short* __restrict__ rank16,
                                              const int* __restrict__ colpre,
                                              const int* __restrict__ offs,
                                              const float* __restrict__ dinv,
                                              float2* __restrict__ epair, int M, int N) {
  int part = blockIdx.x & 7;
  int j    = blockIdx.x >> 3;
  int nj   = gridDim.x >> 3;
  int lo = (int)((long long)part * N >> 3);
  int hi = (int)((long long)(part + 1) * N >> 3);
  for (int i = j * 256 + threadIdx.x; i < M; i += nj * 256) {
    int rec = pk[i];
    int d = rec >> 14;
    if (d < lo || d >= hi) continue;
    int s = rec & 0x3FFF;
    int w = i >> CSHIFT;
    int pos = offs[d] + colpre[w * HS + d] + (int)rank16[i];
    epair[pos] = make_float2(__int_as_float(s), dinv[s] * dinv[d]);
  }
}

// ---------------- GEMM: C[N x 128](bf16) = A[N x 128](f32) @ W[128 x 128](f32) ----------------
__global__ __launch_bounds__(256) void k_gemm(const float* __restrict__ A,
                                              const float* __restrict__ W,
                                              unsigned short* __restrict__ C, int N) {
  __shared__ float As[32][36];
  __shared__ float Ws[32][128];
  int tid = threadIdx.x;
  int tx = tid & 31;
  int ty = tid >> 5;
  int r0 = blockIdx.x * 32;
  float acc[4][4] = {};

  for (int k0 = 0; k0 < 128; k0 += 32) {
    for (int i = tid; i < 1024; i += 256) {
      int kk = i >> 5, j4 = i & 31;
      float4 w = *(const float4*)(W + (size_t)(k0 + kk) * 128 + j4 * 4);
      *(float4*)(&Ws[kk][j4 * 4]) = w;
    }
    {
      int r = tid >> 3, k4 = tid & 7;
      int row = r0 + r;
      float4 a = make_float4(0.f, 0.f, 0.f, 0.f);
      if (row < N) a = *(const float4*)(A + (size_t)row * 128 + k0 + k4 * 4);
      As[k4 * 4 + 0][r] = a.x;
      As[k4 * 4 + 1][r] = a.y;
      As[k4 * 4 + 2][r] = a.z;
      As[k4 * 4 + 3][r] = a.w;
    }
    __syncthreads();
    #pragma unroll
    for (int k = 0; k < 32; ++k) {
      float4 a = *(const float4*)(&As[k][ty * 4]);
      float4 b = *(const float4*)(&Ws[k][tx * 4]);
      float av[4] = {a.x, a.y, a.z, a.w};
      float bv[4] = {b.x, b.y, b.z, b.w};
      #pragma unroll
      for (int i = 0; i < 4; ++i)
        #pragma unroll
        for (int j = 0; j < 4; ++j)
          acc[i][j] = fmaf(av[i], bv[j], acc[i][j]);
    }
    __syncthreads();
  }
  #pragma unroll
  for (int i = 0; i < 4; ++i) {
    int row = r0 + ty * 4 + i;
    if (row < N) {
      ushort4 o;
      o.x = f2bf(acc[i][0]); o.y = f2bf(acc[i][1]);
      o.z = f2bf(acc[i][2]); o.w = f2bf(acc[i][3]);
      *(ushort4*)(C + (size_t)row * 128 + tx * 4) = o;
    }
  }
}

// ---------------- aggregation ----------------
__device__ __forceinline__ void agg_core(const unsigned short* __restrict__ t,
                                         const float2* __restrict__ epair,
                                         int beg, int end, int lane,
                                         float& ax, float& ay) {
  int e = beg;
  for (; e + 16 <= end; e += 16) {
    float2 ep[16];
    #pragma unroll
    for (int u = 0; u < 16; ++u) ep[u] = epair[e + u];
    #pragma unroll
    for (int u = 0; u < 16; ++u) {
      int   s = __float_as_int(ep[u].x);
      float w = ep[u].y;
      unsigned int v = *(const unsigned int*)(t + ((size_t)s << 7) + (lane << 1));
      ax = fmaf(w, __uint_as_float(v << 16), ax);
      ay = fmaf(w, __uint_as_float(v & 0xFFFF0000u), ay);
    }
  }
  for (; e < end; ++e) {
    float2 ep = epair[e];
    int   s = __float_as_int(ep.x);
    float w = ep.y;
    unsigned int v = *(const unsigned int*)(t + ((size_t)s << 7) + (lane << 1));
    ax = fmaf(w, __uint_as_float(v << 16), ax);
    ay = fmaf(w, __uint_as_float(v & 0xFFFF0000u), ay);
  }
}

__global__ __launch_bounds__(256) void k_agg(const unsigned short* __restrict__ t,
                                             const float2* __restrict__ epair,
                                             const int* __restrict__ offs,
                                             const float* __restrict__ bias,
                                             float* __restrict__ hout, int N, int relu) {
  int node = __builtin_amdgcn_readfirstlane(blockIdx.x * 4 + (threadIdx.x >> 6));
  int lane = threadIdx.x & 63;
  if (node >= N) return;
  int beg = offs[node], end = offs[node + 1];
  float ax = 0.f, ay = 0.f;
  agg_core(t, epair, beg, end, lane, ax, ay);
  float2 b = *(const float2*)(bias + lane * 2);
  ax += b.x; ay += b.y;
  if (relu) { ax = fmaxf(ax, 0.f); ay = fmaxf(ay, 0.f); }
  *(float2*)(hout + (size_t)node * 128 + lane * 2) = make_float2(ax, ay);
}

__global__ __launch_bounds__(256) void k_agg_pool(const unsigned short* __restrict__ t,
                                                  const float2* __restrict__ epair,
                                                  const int* __restrict__ offs,
                                                  const float* __restrict__ bias,
                                                  const float* __restrict__ Wp,
                                                  const int* __restrict__ batch,
                                                  float* accB, int N) {
  int node = __builtin_amdgcn_readfirstlane(blockIdx.x * 4 + (threadIdx.x >> 6));
  int lane = threadIdx.x & 63;
  if (node >= N) return;
  int beg = offs[node], end = offs[node + 1];
  float ax = 0.f, ay = 0.f;
  agg_core(t, epair, beg, end, lane, ax, ay);
  float2 b = *(const float2*)(bias + lane * 2);
  float2 wp = *(const float2*)(Wp + lane * 2);
  float p = (ax + b.x) * wp.x + (ay + b.y) * wp.y;
  #pragma unroll
  for (int s = 32; s; s >>= 1) p += __shfl_xor(p, s);
  if (lane == 0) atomicAdd(&accB[batch[node]], p);
}

__global__ __launch_bounds__(64) void k_final(const float* __restrict__ accB,
                                              const int* __restrict__ cntB,
                                              const float* __restrict__ bp,
                                              float* out, int B) {
  int b = blockIdx.x * 64 + threadIdx.x;
  if (b < B) {
    float c = (float)(cntB[b] > 1 ? cntB[b] : 1);
    out[b] = accB[b] / c + bp[0];
  }
}

// ---------------- launch ----------------

extern "C" void kernel_launch(void* const* d_in, const int* in_sizes, int n_in,
                              void* d_out, int out_size, void* d_ws, size_t ws_size,
                              hipStream_t stream) {
  const float* x    = (const float*)d_in[0];
  const int*   ei   = (const int*)d_in[1];
  const int*   batch= (const int*)d_in[2];
  const float* W1   = (const float*)d_in[3];
  const float* b1   = (const float*)d_in[4];
  const float* W2   = (const float*)d_in[5];
  const float* b2   = (const float*)d_in[6];
  const float* W3   = (const float*)d_in[7];
  const float* b3   = (const float*)d_in[8];
  const float* Wp   = (const float*)d_in[9];
  const float* bp   = (const float*)d_in[10];
  float* out = (float*)d_out;

  int N = in_sizes[0] / D;
  int E = in_sizes[1] / 2;
  int B = out_size;
  int M = E + N;
  int HW = (M + CSZ - 1) >> CSHIFT;     // number of chunks

  char* p = (char*)d_ws;
  float2* epair  = (float2*)p;          p += (size_t)M * 8;
  float* hbuf    = (float*)p;           p += (size_t)N * D * 4;
  unsigned short* tbuf = (unsigned short*)p; p += (size_t)N * D * 2;
  int*   pk      = (int*)p;             p += (size_t)M * 4;
  unsigned short* rank16 = (unsigned short*)p; p += (size_t)M * 2;
  int*   g_hist  = (int*)p;             p += (size_t)HW * HS * 4;
  int*   g_bh    = (int*)p;             p += (size_t)HW * 64 * 4;
  int*   cnt     = (int*)p;             p += (size_t)N * 4;
  int*   offs    = (int*)p;             p += (size_t)(N + 1) * 4;
  float* dinv    = (float*)p;           p += (size_t)N * 4;
  float* accB    = (float*)p;           p += (size_t)B * 4;
  int*   cntB    = (int*)p;             p += (size_t)B * 4;

  int gG  = (N + 31) / 32;
  int gA  = (N + 3) / 4;
  int gMg = (N + 255) / 256;

  k_hist <<<HW, 256, 0, stream>>>(ei, E, M, batch, pk, rank16, g_hist, g_bh);
  k_merge<<<gMg, 256, 0, stream>>>(g_hist, g_bh, cnt, dinv, cntB, accB, N, B, HW);
  k_scan <<<1, 1024, 0, stream>>>(cnt, offs, N);
  k_fill <<<4096, 256, 0, stream>>>(pk, rank16, g_hist, offs, dinv, epair, M, N);

  k_gemm<<<gG, 256, 0, stream>>>(x, W1, tbuf, N);
  k_agg <<<gA, 256, 0, stream>>>(tbuf, epair, offs, b1, hbuf, N, 1);
  k_gemm<<<gG, 256, 0, stream>>>(hbuf, W2, tbuf, N);
  k_agg <<<gA, 256, 0, stream>>>(tbuf, epair, offs, b2, hbuf, N, 1);
  k_gemm<<<gG, 256, 0, stream>>>(hbuf, W3, tbuf, N);
  k_agg_pool<<<gA, 256, 0, stream>>>(tbuf, epair, offs, b3, Wp, batch, accB, N);
  k_final<<<(B + 63) / 64, 64, 0, stream>>>(accB, cntB, bp, out, B);
}